// Round 10
// baseline (524.100 us; speedup 1.0000x reference)
//
#include <hip/hip_runtime.h>
#include <stdint.h>

#define DEVI __device__ __forceinline__
typedef unsigned short u16;
typedef __attribute__((ext_vector_type(8))) short bf8v;   // 8 bf16 (4 VGPR)
typedef __attribute__((ext_vector_type(4))) float f4v;    // MFMA acc

DEVI u16 f2bf(float f) {
  union { float f; uint32_t u; } v; v.f = f;
  return (u16)((v.u + 0x7fffu + ((v.u >> 16) & 1u)) >> 16);
}
DEVI float bf2f(u16 b) {
  union { uint32_t u; float f; } v; v.u = ((uint32_t)b) << 16;
  return v.f;
}
DEVI f4v mfma16(bf8v a, bf8v b, f4v c) {
  return __builtin_amdgcn_mfma_f32_16x16x32_bf16(a, b, c, 0, 0, 0);
}
// global->LDS direct copy: HW writes wave-uniform base + lane*16B.
DEVI void gload16(const u16* g, u16* l) {
  const auto* gp = reinterpret_cast<const uint32_t __attribute__((address_space(1)))*>(
      reinterpret_cast<uintptr_t>(g));
  auto* lp = reinterpret_cast<uint32_t __attribute__((address_space(3)))*>(
      reinterpret_cast<uintptr_t>(l));
  __builtin_amdgcn_global_load_lds(gp, lp, 16, 0, 0);
}

// ---------------- prep: 5 weight cvts (blocks 0..3071) + LPU (blocks 3072..7167) ----------------
// cvt: dst is the contiguous wqb..wm2b region; segment lookup on float4 index.
__global__ __launch_bounds__(256) void prep_kernel(
    const float* __restrict__ qw, const float* __restrict__ kvw, const float* __restrict__ pw,
    const float* __restrict__ m1w, const float* __restrict__ m2w, u16* __restrict__ wdst,
    const float* __restrict__ x, float* __restrict__ xp,
    const float* __restrict__ w3a, const float* __restrict__ b3a,
    const float* __restrict__ w51a, const float* __restrict__ b51a,
    const float* __restrict__ w15a, const float* __restrict__ b15a,
    const float* __restrict__ w3b, const float* __restrict__ b3b,
    const float* __restrict__ w51b, const float* __restrict__ b51b,
    const float* __restrict__ w15b, const float* __restrict__ b15b)
{
  __shared__ float xt[36 * 36];
  __shared__ float yt[32 * 36];
  int bid = blockIdx.x;
  if (bid < 3072) {
    int i = bid * 256 + threadIdx.x;          // float4 index, 786432 total
    const float4* s; int local;
    if (i < 65536)       { s = (const float4*)qw;  local = i; }
    else if (i < 196608) { s = (const float4*)kvw; local = i - 65536; }
    else if (i < 262144) { s = (const float4*)pw;  local = i - 196608; }
    else if (i < 524288) { s = (const float4*)m1w; local = i - 262144; }
    else                 { s = (const float4*)m2w; local = i - 524288; }
    float4 v = s[local];
    ushort4 o; o.x = f2bf(v.x); o.y = f2bf(v.y); o.z = f2bf(v.z); o.w = f2bf(v.w);
    ((ushort4*)wdst)[i] = o;
    return;
  }
  int lbid = bid - 3072;
  int cp = lbid & 511, img = (lbid >> 9) & 1, b = lbid >> 10;
  const float* W3  = (img ? w3b  : w3a)  + cp * 9;
  const float* W51 = (img ? w51b : w51a) + cp * 5;
  const float* W15 = (img ? w15b : w15a) + cp * 5;
  float B3  = (img ? b3b  : b3a)[cp];
  float B51 = (img ? b51b : b51a)[cp];
  float B15 = (img ? b15b : b15a)[cp];
  int t = threadIdx.x;
  for (int i = t; i < 36 * 36; i += 256) xt[i] = 0.f;
  for (int i = t; i < 32 * 36; i += 256) yt[i] = 0.f;
  __syncthreads();
  {
    int s = t * 4;
    int row = 4 * cp + 2 * (s >> 9) + img;
    float4 v = *(const float4*)(x + ((size_t)b * 2048 + row) * 512 + (s & 511));
    float* dp = &xt[(2 + (s >> 5)) * 36 + 2 + (s & 31)];
    dp[0] = v.x; dp[1] = v.y; dp[2] = v.z; dp[3] = v.w;
  }
  __syncthreads();
  float w3r[9], w51r[5], w15r[5];
  #pragma unroll
  for (int i = 0; i < 9; i++) w3r[i] = W3[i];
  #pragma unroll
  for (int i = 0; i < 5; i++) { w51r[i] = W51[i]; w15r[i] = W15[i]; }
  #pragma unroll
  for (int pp = 0; pp < 4; pp++) {
    int s = t + pp * 256;
    int i = s >> 5, j = s & 31;
    float a = B51;
    #pragma unroll
    for (int di = 0; di < 5; di++) a += w51r[di] * xt[(i + di) * 36 + 2 + j];
    yt[i * 36 + 2 + j] = a;
  }
  __syncthreads();
  #pragma unroll
  for (int pp = 0; pp < 4; pp++) {
    int s = t + pp * 256;
    int i = s >> 5, j = s & 31;
    float o = 2.f * xt[(2 + i) * 36 + 2 + j] + B3 + B15;
    #pragma unroll
    for (int di = 0; di < 3; di++)
      #pragma unroll
      for (int dj = 0; dj < 3; dj++)
        o += w3r[di * 3 + dj] * xt[(1 + i + di) * 36 + 1 + j + dj];
    #pragma unroll
    for (int dj = 0; dj < 5; dj++) o += w15r[dj] * yt[i * 36 + j + dj];
    xp[((size_t)b * 2048 + img * 1024 + s) * 512 + cp] = o;
  }
}

// ---------------- LayerNorm over 512, 1 wave per row, bf16 out ----------------
__global__ __launch_bounds__(256) void ln_kernel(
    const float* __restrict__ x, const float* __restrict__ w, const float* __restrict__ bb,
    u16* __restrict__ ob)
{
  int row = blockIdx.x * 4 + (threadIdx.x >> 6);
  int lane = threadIdx.x & 63;
  const float4* xr = (const float4*)(x + (size_t)row * 512);
  float4 v0 = xr[lane], v1 = xr[64 + lane];
  float s = v0.x + v0.y + v0.z + v0.w + v1.x + v1.y + v1.z + v1.w;
  #pragma unroll
  for (int off = 32; off; off >>= 1) s += __shfl_xor(s, off);
  float mu = s * (1.f / 512.f);
  float q = 0.f, d;
  d = v0.x - mu; q += d * d;  d = v0.y - mu; q += d * d;
  d = v0.z - mu; q += d * d;  d = v0.w - mu; q += d * d;
  d = v1.x - mu; q += d * d;  d = v1.y - mu; q += d * d;
  d = v1.z - mu; q += d * d;  d = v1.w - mu; q += d * d;
  #pragma unroll
  for (int off = 32; off; off >>= 1) q += __shfl_xor(q, off);
  float rstd = rsqrtf(q * (1.f / 512.f) + 1e-5f);
  const float4* w4 = (const float4*)w;
  const float4* b4 = (const float4*)bb;
  float4 wa = w4[lane], wc = w4[64 + lane], ba = b4[lane], bc = b4[64 + lane];
  ushort4 p0, p1;
  p0.x = f2bf((v0.x - mu) * rstd * wa.x + ba.x);
  p0.y = f2bf((v0.y - mu) * rstd * wa.y + ba.y);
  p0.z = f2bf((v0.z - mu) * rstd * wa.z + ba.z);
  p0.w = f2bf((v0.w - mu) * rstd * wa.w + ba.w);
  p1.x = f2bf((v1.x - mu) * rstd * wc.x + bc.x);
  p1.y = f2bf((v1.y - mu) * rstd * wc.y + bc.y);
  p1.z = f2bf((v1.z - mu) * rstd * wc.z + bc.z);
  p1.w = f2bf((v1.w - mu) * rstd * wc.w + bc.w);
  ushort4* o = (ushort4*)(ob + (size_t)row * 512);
  o[lane] = p0; o[64 + lane] = p1;
}

// ---------------- SR stride-2 dwconvs (bf16 input) -> interleaved xk ----------------
__global__ __launch_bounds__(256) void sr_kernel(
    const u16* __restrict__ xab,
    const float* __restrict__ w1, const float* __restrict__ b1,
    const float* __restrict__ w2, const float* __restrict__ b2,
    float* __restrict__ xk)
{
  __shared__ float img[2048];   // [64][32]
  int bid = blockIdx.x;
  int c = bid & 511, b = bid >> 9;
  int t = threadIdx.x;
  {
    int ii = t * 8;
    int k = ii >> 9, off = ii & 511;
    int perm = (k == 1) ? 2 : ((k == 2) ? 1 : k);  // 0,2,1,3
    bf8v v = *(const bf8v*)&xab[((size_t)b * 2048 + 4 * c + perm) * 512 + off];
    #pragma unroll
    for (int e = 0; e < 8; e++) img[ii + e] = bf2f(((const u16*)&v)[e]);
  }
  __syncthreads();
  float W1[4], W2[4];
  #pragma unroll
  for (int i = 0; i < 4; i++) { W1[i] = w1[c * 4 + i]; W2[i] = w2[c * 4 + i]; }
  float B1 = b1[c], B2 = b2[c];
  #pragma unroll
  for (int pp = 0; pp < 2; pp++) {
    int s = t + pp * 256;
    int p = s >> 4, q = s & 15;
    int u = 2 * p, v = 2 * q;
    float y1 = B1 + W1[0] * img[u * 32 + v]       + W1[1] * img[u * 32 + v + 1]
                  + W1[2] * img[(u + 1) * 32 + v] + W1[3] * img[(u + 1) * 32 + v + 1];
    float y2 = B2;
    #pragma unroll
    for (int di = 0; di < 2; di++)
      #pragma unroll
      for (int dj = 0; dj < 2; dj++) {
        int uu = u + di - 1, vv = v + dj - 1;
        float xv = (uu >= 0 && vv >= 0) ? img[uu * 32 + vv] : 0.f;
        y2 += W2[di * 2 + dj] * xv;
      }
    size_t base = ((size_t)b * 1024 + 2 * s) * 512 + c;
    xk[base] = y1;
    xk[base + 512] = y2;
  }
}

// ---------------- bf16 MFMA GEMM body, 64x128 tile, global_load_lds staging ----------------
// EPI 0: Q layout bf16 [B,H,2048,64]   EPI 1: KV split -> k[B,H,1024,64], vT[B,H,64,1024]
// EPI 2: fp32 out = acc + bias + res   EPI 3: GELU(exact) -> bf16 [M,N]
template<int EPI>
DEVI void gemm_body(int bx, int by,
    const u16* __restrict__ A, const u16* __restrict__ W, const float* __restrict__ bias,
    void* __restrict__ out, const float* __restrict__ res, void* __restrict__ out2,
    int M, int N, int K, u16* As, u16* Bs)
{
  int tid = threadIdx.x;
  int wid = tid >> 6, lane = tid & 63;
  int wr = wid >> 1, wc = wid & 1;
  int l15 = lane & 15, lhi = lane >> 4;
  int m0 = by * 64, n0 = bx * 128;
  f4v acc[2][4] = {};
  int trow = tid >> 2, tcol = (tid & 3) * 8;
  const u16* apg  = &A[(size_t)(m0 + trow) * K + tcol];
  const u16* bpg0 = &W[(size_t)(n0 + trow) * K + tcol];
  const u16* bpg1 = &W[(size_t)(n0 + 64 + trow) * K + tcol];
  u16* al  = &As[tid * 8];
  u16* bl0 = &Bs[tid * 8];
  u16* bl1 = &Bs[2048 + tid * 8];
  for (int k0 = 0; k0 < K; k0 += 32) {
    gload16(apg + k0, al);
    gload16(bpg0 + k0, bl0);
    gload16(bpg1 + k0, bl1);
    __syncthreads();
    bf8v af[2], bfr[4];
    #pragma unroll
    for (int mi = 0; mi < 2; mi++) af[mi] = *(const bf8v*)&As[(wr * 32 + mi * 16 + l15) * 32 + lhi * 8];
    #pragma unroll
    for (int ni = 0; ni < 4; ni++) bfr[ni] = *(const bf8v*)&Bs[(wc * 64 + ni * 16 + l15) * 32 + lhi * 8];
    #pragma unroll
    for (int mi = 0; mi < 2; mi++)
      #pragma unroll
      for (int ni = 0; ni < 4; ni++)
        acc[mi][ni] = mfma16(af[mi], bfr[ni], acc[mi][ni]);
    __syncthreads();
  }
  #pragma unroll
  for (int mi = 0; mi < 2; mi++) {
    #pragma unroll
    for (int ni = 0; ni < 4; ni++) {
      int col = n0 + wc * 64 + ni * 16 + l15;
      float bv = bias[col];
      #pragma unroll
      for (int r = 0; r < 4; r++) {
        int row = m0 + wr * 32 + mi * 16 + lhi * 4 + r;
        float v = acc[mi][ni][r] + bv;
        if (EPI == 0) {
          int b = row >> 11, n = row & 2047, h = col >> 6, dd = col & 63;
          ((u16*)out)[(((size_t)(b * 8 + h) * 2048) + n) * 64 + dd] = f2bf(v);
        } else if (EPI == 1) {
          int b = row >> 10, m = row & 1023;
          if (col < 512) {
            int h = col >> 6, dd = col & 63;
            ((u16*)out)[(((size_t)(b * 8 + h) * 1024) + m) * 64 + dd] = f2bf(v);
          } else {
            int h = (col - 512) >> 6, dd = col & 63;
            ((u16*)out2)[(((size_t)(b * 8 + h) * 64) + dd) * 1024 + m] = f2bf(v);
          }
        } else if (EPI == 2) {
          size_t idx = (size_t)row * N + col;
          ((float*)out)[idx] = v + res[idx];
        } else {
          float g = 0.5f * v * (1.f + erff(v * 0.70710678118f));
          ((u16*)out)[(size_t)row * N + col] = f2bf(g);
        }
      }
    }
  }
}

template<int EPI>
__global__ __launch_bounds__(256) void gemm_one(
    const u16* __restrict__ A, const u16* __restrict__ W, const float* __restrict__ bias,
    void* __restrict__ out, const float* __restrict__ res, void* __restrict__ out2,
    int M, int N, int K)
{
  __shared__ u16 As[64 * 32];
  __shared__ u16 Bs[128 * 32];
  gemm_body<EPI>(blockIdx.x, blockIdx.y, A, W, bias, out, res, out2, M, N, K, As, Bs);
}

// Q-GEMM (blocks 0..511) + KV-GEMM (blocks 512..1023) in one launch.
__global__ __launch_bounds__(256) void gemm_qkv(
    const u16* __restrict__ xab, const u16* __restrict__ wq, const float* __restrict__ qbias,
    void* __restrict__ qout,
    const u16* __restrict__ xkb, const u16* __restrict__ wkv, const float* __restrict__ kvbias,
    void* __restrict__ kout, void* __restrict__ vout)
{
  __shared__ u16 As[64 * 32];
  __shared__ u16 Bs[128 * 32];
  int bid = blockIdx.x;
  if (bid < 512) {
    gemm_body<0>(bid & 3, bid >> 2, xab, wq, qbias, qout, nullptr, nullptr, 8192, 512, 512, As, Bs);
  } else {
    int b2 = bid - 512;
    gemm_body<1>(b2 & 7, b2 >> 3, xkb, wkv, kvbias, kout, nullptr, vout, 4096, 1024, 512, As, Bs);
  }
}

// ---------------- attention with top-k(819/1024) masked softmax ----------------
// bf16 S in LDS (32KB, XOR-swizzled rows); 4-row ILP-interleaved threshold search +
// fused in-register softmax; P overwrites S in place -> 4 blocks/CU.
__global__ __launch_bounds__(256, 4) void attn_kernel(
    const u16* __restrict__ qg, const u16* __restrict__ kg,
    const u16* __restrict__ vTg, u16* __restrict__ sa)
{
  __shared__ u16 S16[16 * 1024];          // row*1024 + (col ^ ((row&7)<<3))
  __shared__ float dn[16];
  int bid = blockIdx.x;
  int qt = bid & 127, bh = bid >> 7;
  int q0 = qt * 16;
  int tid = threadIdx.x, w = tid >> 6, lane = tid & 63;
  int l15 = lane & 15, lhi = lane >> 4;
  const u16* qbase = qg + ((size_t)bh * 2048 + q0) * 64;
  bf8v aq0 = *(const bf8v*)&qbase[l15 * 64 + lhi * 8];
  bf8v aq1 = *(const bf8v*)&qbase[l15 * 64 + 32 + lhi * 8];
  // phase 1: S = (Q K^T) * 0.125, bf16 swizzled; wave w covers k-cols [w*256, w*256+256)
  const u16* kbase = kg + (size_t)bh * 1024 * 64;
  for (int ct = 0; ct < 16; ct++) {
    int kc0 = w * 256 + ct * 16;
    const u16* kb = &kbase[(size_t)(kc0 + l15) * 64 + lhi * 8];
    bf8v bk0 = *(const bf8v*)&kb[0];
    bf8v bk1 = *(const bf8v*)&kb[32];
    f4v a = {};
    a = mfma16(aq0, bk0, a);
    a = mfma16(aq1, bk1, a);
    #pragma unroll
    for (int r = 0; r < 4; r++) {
      int row = lhi * 4 + r;
      int col = kc0 + l15;
      S16[row * 1024 + (col ^ ((row & 7) << 3))] = f2bf(a[r] * 0.125f);
    }
  }
  __syncthreads();
  // phase 2: 4-row interleaved ballot binary search + fused exp + in-place P write.
  // Wave w owns rows 4w..4w+3; 4 independent serial chains give the VALU ILP.
  {
    float vals[4][16];
    #pragma unroll
    for (int rr = 0; rr < 4; rr++) {
      int row = w * 4 + rr;
      int pat = (row & 7) << 3;
      #pragma unroll
      for (int j = 0; j < 16; j++)
        vals[rr][j] = bf2f(S16[row * 1024 + ((j * 64 + lane) ^ pat)]);
    }
    float vmx[4], vmn[4];
    #pragma unroll
    for (int rr = 0; rr < 4; rr++) {
      float a = vals[rr][0], b = vals[rr][0];
      #pragma unroll
      for (int j = 1; j < 16; j++) { a = fmaxf(a, vals[rr][j]); b = fminf(b, vals[rr][j]); }
      vmx[rr] = a; vmn[rr] = b;
    }
    #pragma unroll
    for (int off = 32; off; off >>= 1) {
      #pragma unroll
      for (int rr = 0; rr < 4; rr++) {
        vmx[rr] = fmaxf(vmx[rr], __shfl_xor(vmx[rr], off));
        vmn[rr] = fminf(vmn[rr], __shfl_xor(vmn[rr], off));
      }
    }
    float lo[4], hi[4];
    #pragma unroll
    for (int rr = 0; rr < 4; rr++) { lo[rr] = vmn[rr]; hi[rr] = vmx[rr]; }
    for (int it = 0; it < 14; it++) {
      #pragma unroll
      for (int rr = 0; rr < 4; rr++) {
        float mid = 0.5f * (lo[rr] + hi[rr]);
        int cnt = 0;
        #pragma unroll
        for (int j = 0; j < 16; j++) cnt += (int)__popcll(__ballot(vals[rr][j] >= mid));
        bool ge = (cnt >= 819);
        lo[rr] = ge ? mid : lo[rr];
        hi[rr] = ge ? hi[rr] : mid;
      }
    }
    float ls[4] = {0.f, 0.f, 0.f, 0.f};
    #pragma unroll
    for (int rr = 0; rr < 4; rr++) {
      int row = w * 4 + rr;
      int pat = (row & 7) << 3;
      #pragma unroll
      for (int j = 0; j < 16; j++) {
        float pv = (vals[rr][j] >= lo[rr]) ? __expf(vals[rr][j] - vmx[rr]) : 0.f;
        ls[rr] += pv;
        S16[row * 1024 + ((j * 64 + lane) ^ pat)] = f2bf(pv);
      }
    }
    #pragma unroll
    for (int off = 32; off; off >>= 1) {
      #pragma unroll
      for (int rr = 0; rr < 4; rr++) ls[rr] += __shfl_xor(ls[rr], off);
    }
    if (lane == 0) {
      #pragma unroll
      for (int rr = 0; rr < 4; rr++) dn[w * 4 + rr] = ls[rr];
    }
  }
  __syncthreads();
  // phase 3: out = P * V / dn ; wave w owns d-cols [w*16, w*16+16)
  f4v oacc = {};
  const u16* vb = vTg + ((size_t)bh * 64 + w * 16 + l15) * 1024;
  int patp = (l15 & 7) << 3;
  for (int ks = 0; ks < 32; ks++) {
    int m0 = ks * 32;
    bf8v ap = *(const bf8v*)&S16[l15 * 1024 + ((m0 + lhi * 8) ^ patp)];
    bf8v bv = *(const bf8v*)&vb[m0 + lhi * 8];
    oacc = mfma16(ap, bv, oacc);
  }
  int b = bh >> 3, h = bh & 7;
  #pragma unroll
  for (int r = 0; r < 4; r++) {
    int row = lhi * 4 + r;
    float ov = oacc[r] / dn[row];
    sa[((size_t)b * 2048 + q0 + row) * 512 + h * 64 + w * 16 + l15] = f2bf(ov);
  }
}

extern "C" void kernel_launch(void* const* d_in, const int* in_sizes, int n_in,
                              void* d_out, int out_size, void* d_ws, size_t ws_size,
                              hipStream_t stream) {
  (void)in_sizes; (void)n_in; (void)out_size; (void)ws_size;
  const float* x        = (const float*)d_in[0];
  const float* ln_in_w  = (const float*)d_in[1];
  const float* ln_in_b  = (const float*)d_in[2];
  const float* ln_out_w = (const float*)d_in[3];
  const float* ln_out_b = (const float*)d_in[4];
  const float* sa_w     = (const float*)d_in[5];
  const float* sa_b     = (const float*)d_in[6];
  const float* q_w      = (const float*)d_in[19];
  const float* q_b      = (const float*)d_in[20];
  const float* kv_w     = (const float*)d_in[21];
  const float* kv_b     = (const float*)d_in[22];
  const float* proj_w   = (const float*)d_in[23];
  const float* proj_b   = (const float*)d_in[24];
  const float* sr1_w    = (const float*)d_in[25];
  const float* sr1_b    = (const float*)d_in[26];
  const float* sr2_w    = (const float*)d_in[27];
  const float* sr2_b    = (const float*)d_in[28];
  const float* mlp_w1   = (const float*)d_in[29];
  const float* mlp_b1   = (const float*)d_in[30];
  const float* mlp_w2   = (const float*)d_in[31];
  const float* mlp_b2   = (const float*)d_in[32];

  uint8_t* ws = (uint8_t*)d_ws;
  float* xp   = (float*)(ws + 0);           // 16.78 MB  [B,2048,512]
  u16*  hid   = (u16*)(ws + 0);             // 33.55 MB at MLP stage (xp dead after proj)
  u16*  xab   = (u16*)(ws + 33554432);      // 8.39 MB
  u16*  qb    = (u16*)(ws + 41943040);      // 8.39 MB
  float* xk   = (float*)(ws + 50331648);    // 8.39 MB
  u16*  xkb   = (u16*)(ws + 58720256);      // 4.19 MB
  u16*  kb    = (u16*)(ws + 62914560);      // 4.19 MB
  u16*  vTb   = (u16*)(ws + 67108864);      // 4.19 MB
  u16*  sab   = (u16*)(ws + 71303168);      // 8.39 MB
  float* x2   = (float*)(ws + 79691776);    // 16.78 MB
  u16*  xmb   = (u16*)(ws + 96468992);      // 8.39 MB
  u16*  wqb   = (u16*)(ws + 104857600);     // contiguous cvt dst: wq|wkv|wproj|wm1|wm2
  u16*  wkvb  = (u16*)(ws + 105381888);
  u16*  wprojb= (u16*)(ws + 106430464);
  u16*  wm1b  = (u16*)(ws + 106954752);
  u16*  wm2b  = (u16*)(ws + 109051904);     // end 111149056

  // NOTE: hid aliases xp; xp's last read is proj's res (EPI2) which runs before MLP1. OK.

  prep_kernel<<<dim3(7168), dim3(256), 0, stream>>>(
      q_w, kv_w, proj_w, mlp_w1, mlp_w2, wqb,
      x, xp,
      (const float*)d_in[7],  (const float*)d_in[8],  (const float*)d_in[9],
      (const float*)d_in[10], (const float*)d_in[11], (const float*)d_in[12],
      (const float*)d_in[13], (const float*)d_in[14], (const float*)d_in[15],
      (const float*)d_in[16], (const float*)d_in[17], (const float*)d_in[18]);

  ln_kernel<<<dim3(2048), dim3(256), 0, stream>>>(xp, ln_in_w, ln_in_b, xab);

  sr_kernel<<<dim3(2048), dim3(256), 0, stream>>>(xab, sr1_w, sr1_b, sr2_w, sr2_b, xk);

  ln_kernel<<<dim3(1024), dim3(256), 0, stream>>>(xk, sa_w, sa_b, xkb);

  gemm_qkv<<<dim3(1024), dim3(256), 0, stream>>>(xab, wqb, q_b, (void*)qb,
                                                 xkb, wkvb, kv_b, (void*)kb, (void*)vTb);

  attn_kernel<<<dim3(4096), dim3(256), 0, stream>>>(qb, kb, vTb, sab);

  gemm_one<2><<<dim3(4, 128), dim3(256), 0, stream>>>(sab, wprojb, proj_b, (void*)x2, xp, nullptr, 8192, 512, 512);

  ln_kernel<<<dim3(2048), dim3(256), 0, stream>>>(x2, ln_out_w, ln_out_b, xmb);

  gemm_one<3><<<dim3(16, 128), dim3(256), 0, stream>>>(xmb, wm1b, mlp_b1, (void*)hid, nullptr, nullptr, 8192, 2048, 512);
  gemm_one<2><<<dim3(4, 128), dim3(256), 0, stream>>>(hid, wm2b, mlp_b2, d_out, x2, nullptr, 8192, 512, 2048);
}

// Round 11
// 440.460 us; speedup vs baseline: 1.1899x; 1.1899x over previous
//
#include <hip/hip_runtime.h>
#include <stdint.h>

#define DEVI __device__ __forceinline__
typedef unsigned short u16;
typedef __attribute__((ext_vector_type(8))) short bf8v;   // 8 bf16 (4 VGPR)
typedef __attribute__((ext_vector_type(4))) float f4v;    // MFMA acc

DEVI u16 f2bf(float f) {
  union { float f; uint32_t u; } v; v.f = f;
  return (u16)((v.u + 0x7fffu + ((v.u >> 16) & 1u)) >> 16);
}
DEVI float bf2f(u16 b) {
  union { uint32_t u; float f; } v; v.u = ((uint32_t)b) << 16;
  return v.f;
}
DEVI f4v mfma16(bf8v a, bf8v b, f4v c) {
  return __builtin_amdgcn_mfma_f32_16x16x32_bf16(a, b, c, 0, 0, 0);
}
// global->LDS direct copy: HW writes wave-uniform base + lane*16B.
DEVI void gload16(const u16* g, u16* l) {
  const auto* gp = reinterpret_cast<const uint32_t __attribute__((address_space(1)))*>(
      reinterpret_cast<uintptr_t>(g));
  auto* lp = reinterpret_cast<uint32_t __attribute__((address_space(3)))*>(
      reinterpret_cast<uintptr_t>(l));
  __builtin_amdgcn_global_load_lds(gp, lp, 16, 0, 0);
}

// ---------------- prep: 5 weight cvts (blocks 0..3071) + LPU (blocks 3072..7167) ----------------
// LPU blocks are XCD-chunk swizzled: all 512 channels of one (b,img) image land on one XCD,
// so the 16 partial writers of each 64B xp line share one L2 (write-merge locally).
__global__ __launch_bounds__(256) void prep_kernel(
    const float* __restrict__ qw, const float* __restrict__ kvw, const float* __restrict__ pw,
    const float* __restrict__ m1w, const float* __restrict__ m2w, u16* __restrict__ wdst,
    const float* __restrict__ x, float* __restrict__ xp,
    const float* __restrict__ w3a, const float* __restrict__ b3a,
    const float* __restrict__ w51a, const float* __restrict__ b51a,
    const float* __restrict__ w15a, const float* __restrict__ b15a,
    const float* __restrict__ w3b, const float* __restrict__ b3b,
    const float* __restrict__ w51b, const float* __restrict__ b51b,
    const float* __restrict__ w15b, const float* __restrict__ b15b)
{
  __shared__ float xt[36 * 36];
  __shared__ float yt[32 * 36];
  int bid = blockIdx.x;
  if (bid < 3072) {
    int i = bid * 256 + threadIdx.x;          // float4 index, 786432 total
    const float4* s; int local;
    if (i < 65536)       { s = (const float4*)qw;  local = i; }
    else if (i < 196608) { s = (const float4*)kvw; local = i - 65536; }
    else if (i < 262144) { s = (const float4*)pw;  local = i - 196608; }
    else if (i < 524288) { s = (const float4*)m1w; local = i - 262144; }
    else                 { s = (const float4*)m2w; local = i - 524288; }
    float4 v = s[local];
    ushort4 o; o.x = f2bf(v.x); o.y = f2bf(v.y); o.z = f2bf(v.z); o.w = f2bf(v.w);
    ((ushort4*)wdst)[i] = o;
    return;
  }
  int p = bid - 3072;
  int lbid = (p & 7) * 512 + (p >> 3);        // XCD-chunk swizzle (4096 = 8*512, bijective)
  int cp = lbid & 511, img = (lbid >> 9) & 1, b = lbid >> 10;
  const float* W3  = (img ? w3b  : w3a)  + cp * 9;
  const float* W51 = (img ? w51b : w51a) + cp * 5;
  const float* W15 = (img ? w15b : w15a) + cp * 5;
  float B3  = (img ? b3b  : b3a)[cp];
  float B51 = (img ? b51b : b51a)[cp];
  float B15 = (img ? b15b : b15a)[cp];
  int t = threadIdx.x;
  for (int i = t; i < 36 * 36; i += 256) xt[i] = 0.f;
  for (int i = t; i < 32 * 36; i += 256) yt[i] = 0.f;
  __syncthreads();
  {
    int s = t * 4;
    int row = 4 * cp + 2 * (s >> 9) + img;
    float4 v = *(const float4*)(x + ((size_t)b * 2048 + row) * 512 + (s & 511));
    float* dp = &xt[(2 + (s >> 5)) * 36 + 2 + (s & 31)];
    dp[0] = v.x; dp[1] = v.y; dp[2] = v.z; dp[3] = v.w;
  }
  __syncthreads();
  float w3r[9], w51r[5], w15r[5];
  #pragma unroll
  for (int i = 0; i < 9; i++) w3r[i] = W3[i];
  #pragma unroll
  for (int i = 0; i < 5; i++) { w51r[i] = W51[i]; w15r[i] = W15[i]; }
  #pragma unroll
  for (int pp = 0; pp < 4; pp++) {
    int s = t + pp * 256;
    int i = s >> 5, j = s & 31;
    float a = B51;
    #pragma unroll
    for (int di = 0; di < 5; di++) a += w51r[di] * xt[(i + di) * 36 + 2 + j];
    yt[i * 36 + 2 + j] = a;
  }
  __syncthreads();
  #pragma unroll
  for (int pp = 0; pp < 4; pp++) {
    int s = t + pp * 256;
    int i = s >> 5, j = s & 31;
    float o = 2.f * xt[(2 + i) * 36 + 2 + j] + B3 + B15;
    #pragma unroll
    for (int di = 0; di < 3; di++)
      #pragma unroll
      for (int dj = 0; dj < 3; dj++)
        o += w3r[di * 3 + dj] * xt[(1 + i + di) * 36 + 1 + j + dj];
    #pragma unroll
    for (int dj = 0; dj < 5; dj++) o += w15r[dj] * yt[i * 36 + j + dj];
    xp[((size_t)b * 2048 + img * 1024 + s) * 512 + cp] = o;
  }
}

// ---------------- LayerNorm over 512, 1 wave per row, bf16 out ----------------
__global__ __launch_bounds__(256) void ln_kernel(
    const float* __restrict__ x, const float* __restrict__ w, const float* __restrict__ bb,
    u16* __restrict__ ob)
{
  int row = blockIdx.x * 4 + (threadIdx.x >> 6);
  int lane = threadIdx.x & 63;
  const float4* xr = (const float4*)(x + (size_t)row * 512);
  float4 v0 = xr[lane], v1 = xr[64 + lane];
  float s = v0.x + v0.y + v0.z + v0.w + v1.x + v1.y + v1.z + v1.w;
  #pragma unroll
  for (int off = 32; off; off >>= 1) s += __shfl_xor(s, off);
  float mu = s * (1.f / 512.f);
  float q = 0.f, d;
  d = v0.x - mu; q += d * d;  d = v0.y - mu; q += d * d;
  d = v0.z - mu; q += d * d;  d = v0.w - mu; q += d * d;
  d = v1.x - mu; q += d * d;  d = v1.y - mu; q += d * d;
  d = v1.z - mu; q += d * d;  d = v1.w - mu; q += d * d;
  #pragma unroll
  for (int off = 32; off; off >>= 1) q += __shfl_xor(q, off);
  float rstd = rsqrtf(q * (1.f / 512.f) + 1e-5f);
  const float4* w4 = (const float4*)w;
  const float4* b4 = (const float4*)bb;
  float4 wa = w4[lane], wc = w4[64 + lane], ba = b4[lane], bc = b4[64 + lane];
  ushort4 p0, p1;
  p0.x = f2bf((v0.x - mu) * rstd * wa.x + ba.x);
  p0.y = f2bf((v0.y - mu) * rstd * wa.y + ba.y);
  p0.z = f2bf((v0.z - mu) * rstd * wa.z + ba.z);
  p0.w = f2bf((v0.w - mu) * rstd * wa.w + ba.w);
  p1.x = f2bf((v1.x - mu) * rstd * wc.x + bc.x);
  p1.y = f2bf((v1.y - mu) * rstd * wc.y + bc.y);
  p1.z = f2bf((v1.z - mu) * rstd * wc.z + bc.z);
  p1.w = f2bf((v1.w - mu) * rstd * wc.w + bc.w);
  ushort4* o = (ushort4*)(ob + (size_t)row * 512);
  o[lane] = p0; o[64 + lane] = p1;
}

// ---------------- SR stride-2 dwconvs (bf16 input) -> interleaved xk ----------------
__global__ __launch_bounds__(256) void sr_kernel(
    const u16* __restrict__ xab,
    const float* __restrict__ w1, const float* __restrict__ b1,
    const float* __restrict__ w2, const float* __restrict__ b2,
    float* __restrict__ xk)
{
  __shared__ float img[2048];   // [64][32]
  int bid = blockIdx.x;
  int c = bid & 511, b = bid >> 9;
  int t = threadIdx.x;
  {
    int ii = t * 8;
    int k = ii >> 9, off = ii & 511;
    int perm = (k == 1) ? 2 : ((k == 2) ? 1 : k);  // 0,2,1,3
    bf8v v = *(const bf8v*)&xab[((size_t)b * 2048 + 4 * c + perm) * 512 + off];
    #pragma unroll
    for (int e = 0; e < 8; e++) img[ii + e] = bf2f(((const u16*)&v)[e]);
  }
  __syncthreads();
  float W1[4], W2[4];
  #pragma unroll
  for (int i = 0; i < 4; i++) { W1[i] = w1[c * 4 + i]; W2[i] = w2[c * 4 + i]; }
  float B1 = b1[c], B2 = b2[c];
  #pragma unroll
  for (int pp = 0; pp < 2; pp++) {
    int s = t + pp * 256;
    int p = s >> 4, q = s & 15;
    int u = 2 * p, v = 2 * q;
    float y1 = B1 + W1[0] * img[u * 32 + v]       + W1[1] * img[u * 32 + v + 1]
                  + W1[2] * img[(u + 1) * 32 + v] + W1[3] * img[(u + 1) * 32 + v + 1];
    float y2 = B2;
    #pragma unroll
    for (int di = 0; di < 2; di++)
      #pragma unroll
      for (int dj = 0; dj < 2; dj++) {
        int uu = u + di - 1, vv = v + dj - 1;
        float xv = (uu >= 0 && vv >= 0) ? img[uu * 32 + vv] : 0.f;
        y2 += W2[di * 2 + dj] * xv;
      }
    size_t base = ((size_t)b * 1024 + 2 * s) * 512 + c;
    xk[base] = y1;
    xk[base + 512] = y2;
  }
}

// ---------------- bf16 MFMA GEMM body, 64x128 tile, BK=64, swizzled LDS ----------------
// LDS linear (global_load_lds), global source chunk pre-swizzled cc^(row&7); fragment
// reads apply the same XOR -> conflict-free ds_read_b128 (8 distinct banks / 8 rows).
// EPI 0: Q layout bf16 [B,H,2048,64]   EPI 1: KV split -> k[B,H,1024,64], vT[B,H,64,1024]
// EPI 2: fp32 out = acc + bias + res   EPI 3: GELU(exact) -> bf16 [M,N]
template<int EPI>
DEVI void gemm_body(int bx, int by,
    const u16* __restrict__ A, const u16* __restrict__ W, const float* __restrict__ bias,
    void* __restrict__ out, const float* __restrict__ res, void* __restrict__ out2,
    int M, int N, int K, u16* As, u16* Bs)
{
  int tid = threadIdx.x;
  int wid = tid >> 6, lane = tid & 63;
  int wr = wid >> 1, wc = wid & 1;
  int l15 = lane & 15, lhi = lane >> 4;
  int r7 = l15 & 7;
  int m0 = by * 64, n0 = bx * 128;
  f4v acc[2][4] = {};
  // staging: row = c*32 + (tid>>3), chunk cc = tid&7 (16B units); src chunk = cc ^ (row&7)
  int arow = tid >> 3, cc = tid & 7;
  int sw = (cc ^ (arow & 7)) * 8;
  const u16* apg = &A[(size_t)(m0 + arow) * K + sw];
  const u16* bpg = &W[(size_t)(n0 + arow) * K + sw];
  size_t rstep = (size_t)32 * K;
  u16* al = &As[tid * 8];
  u16* bl = &Bs[tid * 8];
  for (int k0 = 0; k0 < K; k0 += 64) {
    gload16(apg + k0, al);
    gload16(apg + rstep + k0, al + 2048);
    gload16(bpg + k0, bl);
    gload16(bpg + rstep + k0, bl + 2048);
    gload16(bpg + 2 * rstep + k0, bl + 4096);
    gload16(bpg + 3 * rstep + k0, bl + 6144);
    __syncthreads();
    #pragma unroll
    for (int ks = 0; ks < 2; ks++) {
      int ch = ((ks * 4 + lhi) ^ r7) * 8;
      bf8v af[2], bfr[4];
      #pragma unroll
      for (int mi = 0; mi < 2; mi++) af[mi] = *(const bf8v*)&As[(wr * 32 + mi * 16 + l15) * 64 + ch];
      #pragma unroll
      for (int ni = 0; ni < 4; ni++) bfr[ni] = *(const bf8v*)&Bs[(wc * 64 + ni * 16 + l15) * 64 + ch];
      #pragma unroll
      for (int mi = 0; mi < 2; mi++)
        #pragma unroll
        for (int ni = 0; ni < 4; ni++)
          acc[mi][ni] = mfma16(af[mi], bfr[ni], acc[mi][ni]);
    }
    __syncthreads();
  }
  #pragma unroll
  for (int mi = 0; mi < 2; mi++) {
    #pragma unroll
    for (int ni = 0; ni < 4; ni++) {
      int col = n0 + wc * 64 + ni * 16 + l15;
      float bv = bias[col];
      #pragma unroll
      for (int r = 0; r < 4; r++) {
        int row = m0 + wr * 32 + mi * 16 + lhi * 4 + r;
        float v = acc[mi][ni][r] + bv;
        if (EPI == 0) {
          int b = row >> 11, n = row & 2047, h = col >> 6, dd = col & 63;
          ((u16*)out)[(((size_t)(b * 8 + h) * 2048) + n) * 64 + dd] = f2bf(v);
        } else if (EPI == 1) {
          int b = row >> 10, m = row & 1023;
          if (col < 512) {
            int h = col >> 6, dd = col & 63;
            ((u16*)out)[(((size_t)(b * 8 + h) * 1024) + m) * 64 + dd] = f2bf(v);
          } else {
            int h = (col - 512) >> 6, dd = col & 63;
            ((u16*)out2)[(((size_t)(b * 8 + h) * 64) + dd) * 1024 + m] = f2bf(v);
          }
        } else if (EPI == 2) {
          size_t idx = (size_t)row * N + col;
          ((float*)out)[idx] = v + res[idx];
        } else {
          float g = 0.5f * v * (1.f + erff(v * 0.70710678118f));
          ((u16*)out)[(size_t)row * N + col] = f2bf(g);
        }
      }
    }
  }
}

template<int EPI>
__global__ __launch_bounds__(256) void gemm_one(
    const u16* __restrict__ A, const u16* __restrict__ W, const float* __restrict__ bias,
    void* __restrict__ out, const float* __restrict__ res, void* __restrict__ out2,
    int M, int N, int K)
{
  __shared__ u16 As[64 * 64];
  __shared__ u16 Bs[128 * 64];
  gemm_body<EPI>(blockIdx.x, blockIdx.y, A, W, bias, out, res, out2, M, N, K, As, Bs);
}

// Q-GEMM (blocks 0..511) + KV-GEMM (blocks 512..1023) in one launch.
__global__ __launch_bounds__(256) void gemm_qkv(
    const u16* __restrict__ xab, const u16* __restrict__ wq, const float* __restrict__ qbias,
    void* __restrict__ qout,
    const u16* __restrict__ xkb, const u16* __restrict__ wkv, const float* __restrict__ kvbias,
    void* __restrict__ kout, void* __restrict__ vout)
{
  __shared__ u16 As[64 * 64];
  __shared__ u16 Bs[128 * 64];
  int bid = blockIdx.x;
  if (bid < 512) {
    gemm_body<0>(bid & 3, bid >> 2, xab, wq, qbias, qout, nullptr, nullptr, 8192, 512, 512, As, Bs);
  } else {
    int b2 = bid - 512;
    gemm_body<1>(b2 & 7, b2 >> 3, xkb, wkv, kvbias, kout, nullptr, vout, 4096, 1024, 512, As, Bs);
  }
}

// ---------------- attention with top-k(819/1024) masked softmax ----------------
// bf16 S in LDS (32KB, XOR-swizzled rows); single-row fused threshold+softmax (R9 form,
// fits the 64-VGPR cap -> no scratch spill); P overwrites S in place -> 4 blocks/CU.
__global__ __launch_bounds__(256, 4) void attn_kernel(
    const u16* __restrict__ qg, const u16* __restrict__ kg,
    const u16* __restrict__ vTg, u16* __restrict__ sa)
{
  __shared__ u16 S16[16 * 1024];          // row*1024 + (col ^ ((row&7)<<3))
  __shared__ float dn[16];
  int bid = blockIdx.x;
  int qt = bid & 127, bh = bid >> 7;
  int q0 = qt * 16;
  int tid = threadIdx.x, w = tid >> 6, lane = tid & 63;
  int l15 = lane & 15, lhi = lane >> 4;
  const u16* qbase = qg + ((size_t)bh * 2048 + q0) * 64;
  bf8v aq0 = *(const bf8v*)&qbase[l15 * 64 + lhi * 8];
  bf8v aq1 = *(const bf8v*)&qbase[l15 * 64 + 32 + lhi * 8];
  // phase 1: S = (Q K^T) * 0.125, bf16 swizzled; wave w covers k-cols [w*256, w*256+256)
  const u16* kbase = kg + (size_t)bh * 1024 * 64;
  for (int ct = 0; ct < 16; ct++) {
    int kc0 = w * 256 + ct * 16;
    const u16* kb = &kbase[(size_t)(kc0 + l15) * 64 + lhi * 8];
    bf8v bk0 = *(const bf8v*)&kb[0];
    bf8v bk1 = *(const bf8v*)&kb[32];
    f4v a = {};
    a = mfma16(aq0, bk0, a);
    a = mfma16(aq1, bk1, a);
    #pragma unroll
    for (int r = 0; r < 4; r++) {
      int row = lhi * 4 + r;
      int col = kc0 + l15;
      S16[row * 1024 + (col ^ ((row & 7) << 3))] = f2bf(a[r] * 0.125f);
    }
  }
  __syncthreads();
  // phase 2 (fused, one row at a time): ballot binary search (10 iters; scores are
  // bf16-quantized so finer resolution selects the identical set) + exp + in-place P.
  for (int rr = 0; rr < 4; rr++) {
    int row = w * 4 + rr;
    int pat = (row & 7) << 3;
    float vals[16];
    #pragma unroll
    for (int j = 0; j < 16; j++) vals[j] = bf2f(S16[row * 1024 + ((j * 64 + lane) ^ pat)]);
    float vmax = vals[0], vmin = vals[0];
    #pragma unroll
    for (int j = 1; j < 16; j++) { vmax = fmaxf(vmax, vals[j]); vmin = fminf(vmin, vals[j]); }
    #pragma unroll
    for (int off = 32; off; off >>= 1) {
      vmax = fmaxf(vmax, __shfl_xor(vmax, off));
      vmin = fminf(vmin, __shfl_xor(vmin, off));
    }
    float lo = vmin, hi = vmax;
    for (int it = 0; it < 10; it++) {
      float mid = 0.5f * (lo + hi);
      int cnt = 0;
      #pragma unroll
      for (int j = 0; j < 16; j++) cnt += (int)__popcll(__ballot(vals[j] >= mid));
      if (cnt >= 819) lo = mid; else hi = mid;
    }
    float ls = 0.f;
    #pragma unroll
    for (int j = 0; j < 16; j++) {
      float pv = (vals[j] >= lo) ? __expf(vals[j] - vmax) : 0.f;
      ls += pv;
      S16[row * 1024 + ((j * 64 + lane) ^ pat)] = f2bf(pv);
    }
    #pragma unroll
    for (int off = 32; off; off >>= 1) ls += __shfl_xor(ls, off);
    if (lane == 0) dn[row] = ls;
  }
  __syncthreads();
  // phase 3: out = P * V / dn ; wave w owns d-cols [w*16, w*16+16)
  f4v oacc = {};
  const u16* vb = vTg + ((size_t)bh * 64 + w * 16 + l15) * 1024;
  int patp = (l15 & 7) << 3;
  for (int ks = 0; ks < 32; ks++) {
    int m0 = ks * 32;
    bf8v ap = *(const bf8v*)&S16[l15 * 1024 + ((m0 + lhi * 8) ^ patp)];
    bf8v bv = *(const bf8v*)&vb[m0 + lhi * 8];
    oacc = mfma16(ap, bv, oacc);
  }
  int b = bh >> 3, h = bh & 7;
  #pragma unroll
  for (int r = 0; r < 4; r++) {
    int row = lhi * 4 + r;
    float ov = oacc[r] / dn[row];
    sa[((size_t)b * 2048 + q0 + row) * 512 + h * 64 + w * 16 + l15] = f2bf(ov);
  }
}

extern "C" void kernel_launch(void* const* d_in, const int* in_sizes, int n_in,
                              void* d_out, int out_size, void* d_ws, size_t ws_size,
                              hipStream_t stream) {
  (void)in_sizes; (void)n_in; (void)out_size; (void)ws_size;
  const float* x        = (const float*)d_in[0];
  const float* ln_in_w  = (const float*)d_in[1];
  const float* ln_in_b  = (const float*)d_in[2];
  const float* ln_out_w = (const float*)d_in[3];
  const float* ln_out_b = (const float*)d_in[4];
  const float* sa_w     = (const float*)d_in[5];
  const float* sa_b     = (const float*)d_in[6];
  const float* q_w      = (const float*)d_in[19];
  const float* q_b      = (const float*)d_in[20];
  const float* kv_w     = (const float*)d_in[21];
  const float* kv_b     = (const float*)d_in[22];
  const float* proj_w   = (const float*)d_in[23];
  const float* proj_b   = (const float*)d_in[24];
  const float* sr1_w    = (const float*)d_in[25];
  const float* sr1_b    = (const float*)d_in[26];
  const float* sr2_w    = (const float*)d_in[27];
  const float* sr2_b    = (const float*)d_in[28];
  const float* mlp_w1   = (const float*)d_in[29];
  const float* mlp_b1   = (const float*)d_in[30];
  const float* mlp_w2   = (const float*)d_in[31];
  const float* mlp_b2   = (const float*)d_in[32];

  uint8_t* ws = (uint8_t*)d_ws;
  float* xp   = (float*)(ws + 0);           // 16.78 MB  [B,2048,512]
  u16*  hid   = (u16*)(ws + 0);             // 33.55 MB at MLP stage (xp dead after proj)
  u16*  xab   = (u16*)(ws + 33554432);      // 8.39 MB
  u16*  qb    = (u16*)(ws + 41943040);      // 8.39 MB
  float* xk   = (float*)(ws + 50331648);    // 8.39 MB
  u16*  xkb   = (u16*)(ws + 58720256);      // 4.19 MB
  u16*  kb    = (u16*)(ws + 62914560);      // 4.19 MB
  u16*  vTb   = (u16*)(ws + 67108864);      // 4.19 MB
  u16*  sab   = (u16*)(ws + 71303168);      // 8.39 MB
  float* x2   = (float*)(ws + 79691776);    // 16.78 MB
  u16*  xmb   = (u16*)(ws + 96468992);      // 8.39 MB
  u16*  wqb   = (u16*)(ws + 104857600);     // contiguous cvt dst: wq|wkv|wproj|wm1|wm2
  u16*  wkvb  = (u16*)(ws + 105381888);
  u16*  wprojb= (u16*)(ws + 106430464);
  u16*  wm1b  = (u16*)(ws + 106954752);
  u16*  wm2b  = (u16*)(ws + 109051904);     // end 111149056

  prep_kernel<<<dim3(7168), dim3(256), 0, stream>>>(
      q_w, kv_w, proj_w, mlp_w1, mlp_w2, wqb,
      x, xp,
      (const float*)d_in[7],  (const float*)d_in[8],  (const float*)d_in[9],
      (const float*)d_in[10], (const float*)d_in[11], (const float*)d_in[12],
      (const float*)d_in[13], (const float*)d_in[14], (const float*)d_in[15],
      (const float*)d_in[16], (const float*)d_in[17], (const float*)d_in[18]);

  ln_kernel<<<dim3(2048), dim3(256), 0, stream>>>(xp, ln_in_w, ln_in_b, xab);

  sr_kernel<<<dim3(2048), dim3(256), 0, stream>>>(xab, sr1_w, sr1_b, sr2_w, sr2_b, xk);

  ln_kernel<<<dim3(1024), dim3(256), 0, stream>>>(xk, sa_w, sa_b, xkb);

  gemm_qkv<<<dim3(1024), dim3(256), 0, stream>>>(xab, wqb, q_b, (void*)qb,
                                                 xkb, wkvb, kv_b, (void*)kb, (void*)vTb);

  attn_kernel<<<dim3(4096), dim3(256), 0, stream>>>(qb, kb, vTb, sab);

  gemm_one<2><<<dim3(4, 128), dim3(256), 0, stream>>>(sab, wprojb, proj_b, (void*)x2, xp, nullptr, 8192, 512, 512);

  ln_kernel<<<dim3(2048), dim3(256), 0, stream>>>(x2, ln_out_w, ln_out_b, xmb);

  gemm_one<3><<<dim3(16, 128), dim3(256), 0, stream>>>(xmb, wm1b, mlp_b1, (void*)hid, nullptr, nullptr, 8192, 2048, 512);
  gemm_one<2><<<dim3(4, 128), dim3(256), 0, stream>>>(hid, wm2b, mlp_b2, d_out, x2, nullptr, 8192, 512, 2048);
}

// Round 12
// 417.955 us; speedup vs baseline: 1.2540x; 1.0538x over previous
//
#include <hip/hip_runtime.h>
#include <stdint.h>

#define DEVI __device__ __forceinline__
typedef unsigned short u16;
typedef __attribute__((ext_vector_type(8))) short bf8v;   // 8 bf16 (4 VGPR)
typedef __attribute__((ext_vector_type(4))) float f4v;    // MFMA acc

DEVI u16 f2bf(float f) {
  union { float f; uint32_t u; } v; v.f = f;
  return (u16)((v.u + 0x7fffu + ((v.u >> 16) & 1u)) >> 16);
}
DEVI float bf2f(u16 b) {
  union { uint32_t u; float f; } v; v.u = ((uint32_t)b) << 16;
  return v.f;
}
DEVI f4v mfma16(bf8v a, bf8v b, f4v c) {
  return __builtin_amdgcn_mfma_f32_16x16x32_bf16(a, b, c, 0, 0, 0);
}
// global->LDS direct copy: HW writes wave-uniform base + lane*16B.
DEVI void gload16(const u16* g, u16* l) {
  const auto* gp = reinterpret_cast<const uint32_t __attribute__((address_space(1)))*>(
      reinterpret_cast<uintptr_t>(g));
  auto* lp = reinterpret_cast<uint32_t __attribute__((address_space(3)))*>(
      reinterpret_cast<uintptr_t>(l));
  __builtin_amdgcn_global_load_lds(gp, lp, 16, 0, 0);
}

// ---------------- prep: 5 weight cvts (blocks 0..3071) + LPU (blocks 3072..7167) ----------------
// LPU blocks are XCD-chunk swizzled: all 512 channels of one (b,img) image land on one XCD,
// so the 16 partial writers of each 64B xp line share one L2 (write-merge locally).
__global__ __launch_bounds__(256) void prep_kernel(
    const float* __restrict__ qw, const float* __restrict__ kvw, const float* __restrict__ pw,
    const float* __restrict__ m1w, const float* __restrict__ m2w, u16* __restrict__ wdst,
    const float* __restrict__ x, float* __restrict__ xp,
    const float* __restrict__ w3a, const float* __restrict__ b3a,
    const float* __restrict__ w51a, const float* __restrict__ b51a,
    const float* __restrict__ w15a, const float* __restrict__ b15a,
    const float* __restrict__ w3b, const float* __restrict__ b3b,
    const float* __restrict__ w51b, const float* __restrict__ b51b,
    const float* __restrict__ w15b, const float* __restrict__ b15b)
{
  __shared__ float xt[36 * 36];
  __shared__ float yt[32 * 36];
  int bid = blockIdx.x;
  if (bid < 3072) {
    int i = bid * 256 + threadIdx.x;          // float4 index, 786432 total
    const float4* s; int local;
    if (i < 65536)       { s = (const float4*)qw;  local = i; }
    else if (i < 196608) { s = (const float4*)kvw; local = i - 65536; }
    else if (i < 262144) { s = (const float4*)pw;  local = i - 196608; }
    else if (i < 524288) { s = (const float4*)m1w; local = i - 262144; }
    else                 { s = (const float4*)m2w; local = i - 524288; }
    float4 v = s[local];
    ushort4 o; o.x = f2bf(v.x); o.y = f2bf(v.y); o.z = f2bf(v.z); o.w = f2bf(v.w);
    ((ushort4*)wdst)[i] = o;
    return;
  }
  int p = bid - 3072;
  int lbid = (p & 7) * 512 + (p >> 3);        // XCD-chunk swizzle (4096 = 8*512, bijective)
  int cp = lbid & 511, img = (lbid >> 9) & 1, b = lbid >> 10;
  const float* W3  = (img ? w3b  : w3a)  + cp * 9;
  const float* W51 = (img ? w51b : w51a) + cp * 5;
  const float* W15 = (img ? w15b : w15a) + cp * 5;
  float B3  = (img ? b3b  : b3a)[cp];
  float B51 = (img ? b51b : b51a)[cp];
  float B15 = (img ? b15b : b15a)[cp];
  int t = threadIdx.x;
  for (int i = t; i < 36 * 36; i += 256) xt[i] = 0.f;
  for (int i = t; i < 32 * 36; i += 256) yt[i] = 0.f;
  __syncthreads();
  {
    int s = t * 4;
    int row = 4 * cp + 2 * (s >> 9) + img;
    float4 v = *(const float4*)(x + ((size_t)b * 2048 + row) * 512 + (s & 511));
    float* dp = &xt[(2 + (s >> 5)) * 36 + 2 + (s & 31)];
    dp[0] = v.x; dp[1] = v.y; dp[2] = v.z; dp[3] = v.w;
  }
  __syncthreads();
  float w3r[9], w51r[5], w15r[5];
  #pragma unroll
  for (int i = 0; i < 9; i++) w3r[i] = W3[i];
  #pragma unroll
  for (int i = 0; i < 5; i++) { w51r[i] = W51[i]; w15r[i] = W15[i]; }
  #pragma unroll
  for (int pp = 0; pp < 4; pp++) {
    int s = t + pp * 256;
    int i = s >> 5, j = s & 31;
    float a = B51;
    #pragma unroll
    for (int di = 0; di < 5; di++) a += w51r[di] * xt[(i + di) * 36 + 2 + j];
    yt[i * 36 + 2 + j] = a;
  }
  __syncthreads();
  #pragma unroll
  for (int pp = 0; pp < 4; pp++) {
    int s = t + pp * 256;
    int i = s >> 5, j = s & 31;
    float o = 2.f * xt[(2 + i) * 36 + 2 + j] + B3 + B15;
    #pragma unroll
    for (int di = 0; di < 3; di++)
      #pragma unroll
      for (int dj = 0; dj < 3; dj++)
        o += w3r[di * 3 + dj] * xt[(1 + i + di) * 36 + 1 + j + dj];
    #pragma unroll
    for (int dj = 0; dj < 5; dj++) o += w15r[dj] * yt[i * 36 + j + dj];
    xp[((size_t)b * 2048 + img * 1024 + s) * 512 + cp] = o;
  }
}

// ---------------- LayerNorm over 512, 1 wave per row, bf16 out ----------------
__global__ __launch_bounds__(256) void ln_kernel(
    const float* __restrict__ x, const float* __restrict__ w, const float* __restrict__ bb,
    u16* __restrict__ ob)
{
  int row = blockIdx.x * 4 + (threadIdx.x >> 6);
  int lane = threadIdx.x & 63;
  const float4* xr = (const float4*)(x + (size_t)row * 512);
  float4 v0 = xr[lane], v1 = xr[64 + lane];
  float s = v0.x + v0.y + v0.z + v0.w + v1.x + v1.y + v1.z + v1.w;
  #pragma unroll
  for (int off = 32; off; off >>= 1) s += __shfl_xor(s, off);
  float mu = s * (1.f / 512.f);
  float q = 0.f, d;
  d = v0.x - mu; q += d * d;  d = v0.y - mu; q += d * d;
  d = v0.z - mu; q += d * d;  d = v0.w - mu; q += d * d;
  d = v1.x - mu; q += d * d;  d = v1.y - mu; q += d * d;
  d = v1.z - mu; q += d * d;  d = v1.w - mu; q += d * d;
  #pragma unroll
  for (int off = 32; off; off >>= 1) q += __shfl_xor(q, off);
  float rstd = rsqrtf(q * (1.f / 512.f) + 1e-5f);
  const float4* w4 = (const float4*)w;
  const float4* b4 = (const float4*)bb;
  float4 wa = w4[lane], wc = w4[64 + lane], ba = b4[lane], bc = b4[64 + lane];
  ushort4 p0, p1;
  p0.x = f2bf((v0.x - mu) * rstd * wa.x + ba.x);
  p0.y = f2bf((v0.y - mu) * rstd * wa.y + ba.y);
  p0.z = f2bf((v0.z - mu) * rstd * wa.z + ba.z);
  p0.w = f2bf((v0.w - mu) * rstd * wa.w + ba.w);
  p1.x = f2bf((v1.x - mu) * rstd * wc.x + bc.x);
  p1.y = f2bf((v1.y - mu) * rstd * wc.y + bc.y);
  p1.z = f2bf((v1.z - mu) * rstd * wc.z + bc.z);
  p1.w = f2bf((v1.w - mu) * rstd * wc.w + bc.w);
  ushort4* o = (ushort4*)(ob + (size_t)row * 512);
  o[lane] = p0; o[64 + lane] = p1;
}

// ---------------- SR stride-2 dwconvs (bf16 input) -> interleaved xk ----------------
__global__ __launch_bounds__(256) void sr_kernel(
    const u16* __restrict__ xab,
    const float* __restrict__ w1, const float* __restrict__ b1,
    const float* __restrict__ w2, const float* __restrict__ b2,
    float* __restrict__ xk)
{
  __shared__ float img[2048];   // [64][32]
  int bid = blockIdx.x;
  int c = bid & 511, b = bid >> 9;
  int t = threadIdx.x;
  {
    int ii = t * 8;
    int k = ii >> 9, off = ii & 511;
    int perm = (k == 1) ? 2 : ((k == 2) ? 1 : k);  // 0,2,1,3
    bf8v v = *(const bf8v*)&xab[((size_t)b * 2048 + 4 * c + perm) * 512 + off];
    #pragma unroll
    for (int e = 0; e < 8; e++) img[ii + e] = bf2f(((const u16*)&v)[e]);
  }
  __syncthreads();
  float W1[4], W2[4];
  #pragma unroll
  for (int i = 0; i < 4; i++) { W1[i] = w1[c * 4 + i]; W2[i] = w2[c * 4 + i]; }
  float B1 = b1[c], B2 = b2[c];
  #pragma unroll
  for (int pp = 0; pp < 2; pp++) {
    int s = t + pp * 256;
    int p = s >> 4, q = s & 15;
    int u = 2 * p, v = 2 * q;
    float y1 = B1 + W1[0] * img[u * 32 + v]       + W1[1] * img[u * 32 + v + 1]
                  + W1[2] * img[(u + 1) * 32 + v] + W1[3] * img[(u + 1) * 32 + v + 1];
    float y2 = B2;
    #pragma unroll
    for (int di = 0; di < 2; di++)
      #pragma unroll
      for (int dj = 0; dj < 2; dj++) {
        int uu = u + di - 1, vv = v + dj - 1;
        float xv = (uu >= 0 && vv >= 0) ? img[uu * 32 + vv] : 0.f;
        y2 += W2[di * 2 + dj] * xv;
      }
    size_t base = ((size_t)b * 1024 + 2 * s) * 512 + c;
    xk[base] = y1;
    xk[base + 512] = y2;
  }
}

// ---------------- bf16 MFMA GEMM body, 64x128 tile, BK=64, swizzled LDS ----------------
// LDS linear (global_load_lds), global source chunk pre-swizzled cc^(row&7); fragment
// reads apply the same XOR -> conflict-free ds_read_b128 (8 distinct banks / 8 rows).
// EPI 0: Q layout bf16 [B,H,2048,64]   EPI 1: KV split -> k[B,H,1024,64], vT[B,H,64,1024]
// EPI 2: fp32 out = acc + bias + res   EPI 3: GELU(exact) -> bf16 [M,N]
template<int EPI>
DEVI void gemm_body(int bx, int by,
    const u16* __restrict__ A, const u16* __restrict__ W, const float* __restrict__ bias,
    void* __restrict__ out, const float* __restrict__ res, void* __restrict__ out2,
    int M, int N, int K, u16* As, u16* Bs)
{
  int tid = threadIdx.x;
  int wid = tid >> 6, lane = tid & 63;
  int wr = wid >> 1, wc = wid & 1;
  int l15 = lane & 15, lhi = lane >> 4;
  int r7 = l15 & 7;
  int m0 = by * 64, n0 = bx * 128;
  f4v acc[2][4] = {};
  // staging: row = c*32 + (tid>>3), chunk cc = tid&7 (16B units); src chunk = cc ^ (row&7)
  int arow = tid >> 3, cc = tid & 7;
  int sw = (cc ^ (arow & 7)) * 8;
  const u16* apg = &A[(size_t)(m0 + arow) * K + sw];
  const u16* bpg = &W[(size_t)(n0 + arow) * K + sw];
  size_t rstep = (size_t)32 * K;
  u16* al = &As[tid * 8];
  u16* bl = &Bs[tid * 8];
  for (int k0 = 0; k0 < K; k0 += 64) {
    gload16(apg + k0, al);
    gload16(apg + rstep + k0, al + 2048);
    gload16(bpg + k0, bl);
    gload16(bpg + rstep + k0, bl + 2048);
    gload16(bpg + 2 * rstep + k0, bl + 4096);
    gload16(bpg + 3 * rstep + k0, bl + 6144);
    __syncthreads();
    #pragma unroll
    for (int ks = 0; ks < 2; ks++) {
      int ch = ((ks * 4 + lhi) ^ r7) * 8;
      bf8v af[2], bfr[4];
      #pragma unroll
      for (int mi = 0; mi < 2; mi++) af[mi] = *(const bf8v*)&As[(wr * 32 + mi * 16 + l15) * 64 + ch];
      #pragma unroll
      for (int ni = 0; ni < 4; ni++) bfr[ni] = *(const bf8v*)&Bs[(wc * 64 + ni * 16 + l15) * 64 + ch];
      #pragma unroll
      for (int mi = 0; mi < 2; mi++)
        #pragma unroll
        for (int ni = 0; ni < 4; ni++)
          acc[mi][ni] = mfma16(af[mi], bfr[ni], acc[mi][ni]);
    }
    __syncthreads();
  }
  #pragma unroll
  for (int mi = 0; mi < 2; mi++) {
    #pragma unroll
    for (int ni = 0; ni < 4; ni++) {
      int col = n0 + wc * 64 + ni * 16 + l15;
      float bv = bias[col];
      #pragma unroll
      for (int r = 0; r < 4; r++) {
        int row = m0 + wr * 32 + mi * 16 + lhi * 4 + r;
        float v = acc[mi][ni][r] + bv;
        if (EPI == 0) {
          int b = row >> 11, n = row & 2047, h = col >> 6, dd = col & 63;
          ((u16*)out)[(((size_t)(b * 8 + h) * 2048) + n) * 64 + dd] = f2bf(v);
        } else if (EPI == 1) {
          int b = row >> 10, m = row & 1023;
          if (col < 512) {
            int h = col >> 6, dd = col & 63;
            ((u16*)out)[(((size_t)(b * 8 + h) * 1024) + m) * 64 + dd] = f2bf(v);
          } else {
            int h = (col - 512) >> 6, dd = col & 63;
            ((u16*)out2)[(((size_t)(b * 8 + h) * 64) + dd) * 1024 + m] = f2bf(v);
          }
        } else if (EPI == 2) {
          size_t idx = (size_t)row * N + col;
          ((float*)out)[idx] = v + res[idx];
        } else {
          float g = 0.5f * v * (1.f + erff(v * 0.70710678118f));
          ((u16*)out)[(size_t)row * N + col] = f2bf(g);
        }
      }
    }
  }
}

template<int EPI>
__global__ __launch_bounds__(256) void gemm_one(
    const u16* __restrict__ A, const u16* __restrict__ W, const float* __restrict__ bias,
    void* __restrict__ out, const float* __restrict__ res, void* __restrict__ out2,
    int M, int N, int K)
{
  __shared__ u16 As[64 * 64];
  __shared__ u16 Bs[128 * 64];
  gemm_body<EPI>(blockIdx.x, blockIdx.y, A, W, bias, out, res, out2, M, N, K, As, Bs);
}

// Q-GEMM (blocks 0..511) + KV-GEMM (blocks 512..1023) in one launch.
__global__ __launch_bounds__(256) void gemm_qkv(
    const u16* __restrict__ xab, const u16* __restrict__ wq, const float* __restrict__ qbias,
    void* __restrict__ qout,
    const u16* __restrict__ xkb, const u16* __restrict__ wkv, const float* __restrict__ kvbias,
    void* __restrict__ kout, void* __restrict__ vout)
{
  __shared__ u16 As[64 * 64];
  __shared__ u16 Bs[128 * 64];
  int bid = blockIdx.x;
  if (bid < 512) {
    gemm_body<0>(bid & 3, bid >> 2, xab, wq, qbias, qout, nullptr, nullptr, 8192, 512, 512, As, Bs);
  } else {
    int b2 = bid - 512;
    gemm_body<1>(b2 & 7, b2 >> 3, xkb, wkv, kvbias, kout, nullptr, vout, 4096, 1024, 512, As, Bs);
  }
}

// ---------------- attention with top-k(819/1024) masked softmax ----------------
// bf16 S in LDS (32KB, XOR-swizzled rows); phase 2: lane owns 16 contiguous cols
// (2x ds_read_b128 per row) + 2-row-interleaved ballot search (2 independent serial
// chains in flight); P overwrites S in place -> 4 blocks/CU (LDS-bound).
__global__ __launch_bounds__(256, 2) void attn_kernel(
    const u16* __restrict__ qg, const u16* __restrict__ kg,
    const u16* __restrict__ vTg, u16* __restrict__ sa)
{
  __shared__ u16 S16[16 * 1024];          // row*1024 + (col ^ ((row&7)<<3))
  __shared__ float dn[16];
  int bid = blockIdx.x;
  int qt = bid & 127, bh = bid >> 7;
  int q0 = qt * 16;
  int tid = threadIdx.x, w = tid >> 6, lane = tid & 63;
  int l15 = lane & 15, lhi = lane >> 4;
  const u16* qbase = qg + ((size_t)bh * 2048 + q0) * 64;
  bf8v aq0 = *(const bf8v*)&qbase[l15 * 64 + lhi * 8];
  bf8v aq1 = *(const bf8v*)&qbase[l15 * 64 + 32 + lhi * 8];
  // phase 1: S = (Q K^T) * 0.125, bf16 swizzled; wave w covers k-cols [w*256, w*256+256)
  const u16* kbase = kg + (size_t)bh * 1024 * 64;
  for (int ct = 0; ct < 16; ct++) {
    int kc0 = w * 256 + ct * 16;
    const u16* kb = &kbase[(size_t)(kc0 + l15) * 64 + lhi * 8];
    bf8v bk0 = *(const bf8v*)&kb[0];
    bf8v bk1 = *(const bf8v*)&kb[32];
    f4v a = {};
    a = mfma16(aq0, bk0, a);
    a = mfma16(aq1, bk1, a);
    #pragma unroll
    for (int r = 0; r < 4; r++) {
      int row = lhi * 4 + r;
      int col = kc0 + l15;
      S16[row * 1024 + (col ^ ((row & 7) << 3))] = f2bf(a[r] * 0.125f);
    }
  }
  __syncthreads();
  // phase 2: 2-row interleaved. Lane L owns cols [16L,16L+16) of each row; with the
  // XOR swizzle those are exactly two aligned b128 blocks at (16L)^pat and ((16L)^pat)^8.
  #pragma unroll
  for (int rp = 0; rp < 2; rp++) {
    int rowA = w * 4 + rp * 2, rowB = rowA + 1;
    int patA = (rowA & 7) << 3, patB = (rowB & 7) << 3;
    int cA = (lane * 16) ^ patA, cB = (lane * 16) ^ patB;
    u16* SA = &S16[rowA * 1024];
    u16* SB = &S16[rowB * 1024];
    bf8v a0 = *(const bf8v*)&SA[cA];
    bf8v a1 = *(const bf8v*)&SA[cA ^ 8];
    bf8v b0 = *(const bf8v*)&SB[cB];
    bf8v b1 = *(const bf8v*)&SB[cB ^ 8];
    float va[16], vb[16];
    #pragma unroll
    for (int e = 0; e < 8; e++) {
      va[e] = bf2f((u16)a0[e]); va[8 + e] = bf2f((u16)a1[e]);
      vb[e] = bf2f((u16)b0[e]); vb[8 + e] = bf2f((u16)b1[e]);
    }
    float mxA = va[0], mnA = va[0], mxB = vb[0], mnB = vb[0];
    #pragma unroll
    for (int j = 1; j < 16; j++) {
      mxA = fmaxf(mxA, va[j]); mnA = fminf(mnA, va[j]);
      mxB = fmaxf(mxB, vb[j]); mnB = fminf(mnB, vb[j]);
    }
    #pragma unroll
    for (int off = 32; off; off >>= 1) {
      mxA = fmaxf(mxA, __shfl_xor(mxA, off)); mnA = fminf(mnA, __shfl_xor(mnA, off));
      mxB = fmaxf(mxB, __shfl_xor(mxB, off)); mnB = fminf(mnB, __shfl_xor(mnB, off));
    }
    float loA = mnA, hiA = mxA, loB = mnB, hiB = mxB;
    for (int it = 0; it < 10; it++) {
      float midA = 0.5f * (loA + hiA), midB = 0.5f * (loB + hiB);
      int cntA = 0, cntB = 0;
      #pragma unroll
      for (int j = 0; j < 16; j++) {
        cntA += (int)__popcll(__ballot(va[j] >= midA));
        cntB += (int)__popcll(__ballot(vb[j] >= midB));
      }
      bool gA = cntA >= 819, gB = cntB >= 819;
      loA = gA ? midA : loA; hiA = gA ? hiA : midA;
      loB = gB ? midB : loB; hiB = gB ? hiB : midB;
    }
    float lsA = 0.f, lsB = 0.f;
    bf8v pa0, pa1, pb0, pb1;
    #pragma unroll
    for (int e = 0; e < 8; e++) {
      float p;
      p = (va[e] >= loA)     ? __expf(va[e] - mxA)     : 0.f;  lsA += p; pa0[e] = (short)f2bf(p);
      p = (va[8 + e] >= loA) ? __expf(va[8 + e] - mxA) : 0.f;  lsA += p; pa1[e] = (short)f2bf(p);
      p = (vb[e] >= loB)     ? __expf(vb[e] - mxB)     : 0.f;  lsB += p; pb0[e] = (short)f2bf(p);
      p = (vb[8 + e] >= loB) ? __expf(vb[8 + e] - mxB) : 0.f;  lsB += p; pb1[e] = (short)f2bf(p);
    }
    *(bf8v*)&SA[cA] = pa0;      *(bf8v*)&SA[cA ^ 8] = pa1;
    *(bf8v*)&SB[cB] = pb0;      *(bf8v*)&SB[cB ^ 8] = pb1;
    #pragma unroll
    for (int off = 32; off; off >>= 1) {
      lsA += __shfl_xor(lsA, off); lsB += __shfl_xor(lsB, off);
    }
    if (lane == 0) { dn[rowA] = lsA; dn[rowB] = lsB; }
  }
  __syncthreads();
  // phase 3: out = P * V / dn ; wave w owns d-cols [w*16, w*16+16)
  f4v oacc = {};
  const u16* vb = vTg + ((size_t)bh * 64 + w * 16 + l15) * 1024;
  int patp = (l15 & 7) << 3;
  __builtin_amdgcn_s_setprio(1);
  for (int ks = 0; ks < 32; ks++) {
    int m0 = ks * 32;
    bf8v ap = *(const bf8v*)&S16[l15 * 1024 + ((m0 + lhi * 8) ^ patp)];
    bf8v bv = *(const bf8v*)&vb[m0 + lhi * 8];
    oacc = mfma16(ap, bv, oacc);
  }
  __builtin_amdgcn_s_setprio(0);
  int b = bh >> 3, h = bh & 7;
  #pragma unroll
  for (int r = 0; r < 4; r++) {
    int row = lhi * 4 + r;
    float ov = oacc[r] / dn[row];
    sa[((size_t)b * 2048 + q0 + row) * 512 + h * 64 + w * 16 + l15] = f2bf(ov);
  }
}

extern "C" void kernel_launch(void* const* d_in, const int* in_sizes, int n_in,
                              void* d_out, int out_size, void* d_ws, size_t ws_size,
                              hipStream_t stream) {
  (void)in_sizes; (void)n_in; (void)out_size; (void)ws_size;
  const float* x        = (const float*)d_in[0];
  const float* ln_in_w  = (const float*)d_in[1];
  const float* ln_in_b  = (const float*)d_in[2];
  const float* ln_out_w = (const float*)d_in[3];
  const float* ln_out_b = (const float*)d_in[4];
  const float* sa_w     = (const float*)d_in[5];
  const float* sa_b     = (const float*)d_in[6];
  const float* q_w      = (const float*)d_in[19];
  const float* q_b      = (const float*)d_in[20];
  const float* kv_w     = (const float*)d_in[21];
  const float* kv_b     = (const float*)d_in[22];
  const float* proj_w   = (const float*)d_in[23];
  const float* proj_b   = (const float*)d_in[24];
  const float* sr1_w    = (const float*)d_in[25];
  const float* sr1_b    = (const float*)d_in[26];
  const float* sr2_w    = (const float*)d_in[27];
  const float* sr2_b    = (const float*)d_in[28];
  const float* mlp_w1   = (const float*)d_in[29];
  const float* mlp_b1   = (const float*)d_in[30];
  const float* mlp_w2   = (const float*)d_in[31];
  const float* mlp_b2   = (const float*)d_in[32];

  uint8_t* ws = (uint8_t*)d_ws;
  float* xp   = (float*)(ws + 0);           // 16.78 MB  [B,2048,512]
  u16*  hid   = (u16*)(ws + 0);             // 33.55 MB at MLP stage (xp dead after proj)
  u16*  xab   = (u16*)(ws + 33554432);      // 8.39 MB
  u16*  qb    = (u16*)(ws + 41943040);      // 8.39 MB
  float* xk   = (float*)(ws + 50331648);    // 8.39 MB
  u16*  xkb   = (u16*)(ws + 58720256);      // 4.19 MB
  u16*  kb    = (u16*)(ws + 62914560);      // 4.19 MB
  u16*  vTb   = (u16*)(ws + 67108864);      // 4.19 MB
  u16*  sab   = (u16*)(ws + 71303168);      // 8.39 MB
  float* x2   = (float*)(ws + 79691776);    // 16.78 MB
  u16*  xmb   = (u16*)(ws + 96468992);      // 8.39 MB
  u16*  wqb   = (u16*)(ws + 104857600);     // contiguous cvt dst: wq|wkv|wproj|wm1|wm2
  u16*  wkvb  = (u16*)(ws + 105381888);
  u16*  wprojb= (u16*)(ws + 106430464);
  u16*  wm1b  = (u16*)(ws + 106954752);
  u16*  wm2b  = (u16*)(ws + 109051904);     // end 111149056

  prep_kernel<<<dim3(7168), dim3(256), 0, stream>>>(
      q_w, kv_w, proj_w, mlp_w1, mlp_w2, wqb,
      x, xp,
      (const float*)d_in[7],  (const float*)d_in[8],  (const float*)d_in[9],
      (const float*)d_in[10], (const float*)d_in[11], (const float*)d_in[12],
      (const float*)d_in[13], (const float*)d_in[14], (const float*)d_in[15],
      (const float*)d_in[16], (const float*)d_in[17], (const float*)d_in[18]);

  ln_kernel<<<dim3(2048), dim3(256), 0, stream>>>(xp, ln_in_w, ln_in_b, xab);

  sr_kernel<<<dim3(2048), dim3(256), 0, stream>>>(xab, sr1_w, sr1_b, sr2_w, sr2_b, xk);

  ln_kernel<<<dim3(1024), dim3(256), 0, stream>>>(xk, sa_w, sa_b, xkb);

  gemm_qkv<<<dim3(1024), dim3(256), 0, stream>>>(xab, wqb, q_b, (void*)qb,
                                                 xkb, wkvb, kv_b, (void*)kb, (void*)vTb);

  attn_kernel<<<dim3(4096), dim3(256), 0, stream>>>(qb, kb, vTb, sab);

  gemm_one<2><<<dim3(4, 128), dim3(256), 0, stream>>>(sab, wprojb, proj_b, (void*)x2, xp, nullptr, 8192, 512, 512);

  ln_kernel<<<dim3(2048), dim3(256), 0, stream>>>(x2, ln_out_w, ln_out_b, xmb);

  gemm_one<3><<<dim3(16, 128), dim3(256), 0, stream>>>(xmb, wm1b, mlp_b1, (void*)hid, nullptr, nullptr, 8192, 2048, 512);
  gemm_one<2><<<dim3(4, 128), dim3(256), 0, stream>>>(hid, wm2b, mlp_b2, d_out, x2, nullptr, 8192, 512, 2048);
}